// Round 15
// baseline (204.407 us; speedup 1.0000x reference)
//
#include <hip/hip_runtime.h>

typedef __bf16 bf16_t;
typedef __bf16 bf16x4_t __attribute__((ext_vector_type(4)));
typedef __bf16 bf16x8_t __attribute__((ext_vector_type(8)));
typedef float f32x16_t __attribute__((ext_vector_type(16)));

#define AS_G(p) ((const __attribute__((address_space(1))) void*)(p))
#define AS_L(p) ((__attribute__((address_space(3))) void*)(p))
// R11 post-mortem: vmcnt drain before a barrier publishing global_load_lds
// data must be EXPLICIT (__syncthreads alone was replay-flaky).
#define DRAIN_VM() asm volatile("s_waitcnt vmcnt(0)" ::: "memory")

// ---------------------------------------------------------------------------
// Weight repack (oc, ic, ky, kx) fp32 -> bf16 in MFMA B-fragment order:
//   frag f = th*16 + kc*4 + nt*2 + wc,  th = t*2+hk  (frag = 1024 B, lane*16B)
//   lane -> oc = wc*64 + nt*32 + (lane&31); ic = (hk*8 + kc*2 + (lane>>5))*8 + e
// ---------------------------------------------------------------------------
__device__ __forceinline__ void repack_body(const float* __restrict__ w,
                                            bf16_t* __restrict__ wt2,
                                            int o) {
  int e = o & 7;
  int lane = (o >> 3) & 63;
  int f = o >> 9;
  int wc = f & 1;
  int nt = (f >> 1) & 1;
  int kc = (f >> 2) & 3;
  int hk = (f >> 4) & 1;
  int t = f >> 5;
  int oc = wc * 64 + nt * 32 + (lane & 31);
  int ic = (hk * 8 + kc * 2 + (lane >> 5)) * 8 + e;
  wt2[o] = (bf16_t)w[((size_t)oc * 128 + ic) * 9 + t];
}

// ---------------------------------------------------------------------------
// DWT body (explicit block coords): in fp32 (B,32,2h,2w) ->
//   sub bf16 NHWC (B,h,w,128) ci=4c+q  [+ ll fp32 (B,32,h,w)]
// ---------------------------------------------------------------------------
__device__ __forceinline__ void dwt_body(const float* __restrict__ in,
                                         bf16_t* __restrict__ sub,
                                         float* __restrict__ llout,
                                         int h, int w, int bi, int i, int j0,
                                         bf16_t* lds) {
  const int tid = threadIdx.x;
  const int j = tid & 63;
  const int cg = tid >> 6;
  const int jg = j0 + j;
  const bool jok = jg < w;
  const int H2 = h * 2, W2 = w * 2;
  for (int c = cg; c < 32; c += 4) {
    float va = 0.f, vb = 0.f, vc = 0.f, vd = 0.f;
    if (jok) {
      const float2* p0 = (const float2*)(in + ((size_t)(bi * 32 + c) * H2 + 2 * i) * W2);
      const float2* p1 = (const float2*)(in + ((size_t)(bi * 32 + c) * H2 + 2 * i + 1) * W2);
      float2 r0 = p0[jg];
      float2 r1 = p1[jg];
      va = r0.x; vb = r0.y; vc = r1.x; vd = r1.y;
    }
    float ll = (va + vb + vc + vd) * 0.5f;
    float lh = (va - vb + vc - vd) * 0.5f;
    float hl = (va + vb - vc - vd) * 0.5f;
    float hh = (va - vb - vc + vd) * 0.5f;
    bf16x4_t q;
    q.x = (bf16_t)ll; q.y = (bf16_t)lh; q.z = (bf16_t)hl; q.w = (bf16_t)hh;
    *(bf16x4_t*)(&lds[j * 132 + c * 4]) = q;
    if (llout != nullptr && jok)
      llout[((size_t)(bi * 32 + c) * h + i) * w + jg] = ll;
  }
  __syncthreads();
  const size_t obase = ((size_t)bi * h + i) * w;
  for (int it = 0; it < 8; ++it) {
    int flat = it * 256 + tid;
    int jj = flat >> 5;
    int c4 = flat & 31;
    if (j0 + jj < w) {
      bf16x4_t q = *(const bf16x4_t*)(&lds[jj * 132 + c4 * 4]);
      *(bf16x4_t*)(sub + ((obase + j0 + jj) << 7) + c4 * 4) = q;
    }
  }
}

// ---------------------------------------------------------------------------
// ll0 + repack kernel: grid (2,112,9). z<8: ll-only pass over x. z==8: repack.
// ---------------------------------------------------------------------------
__global__ __launch_bounds__(256) void ll0r_kernel(const float* __restrict__ in,
                                                   float* __restrict__ llout,
                                                   const float* __restrict__ wsrc,
                                                   bf16_t* __restrict__ wt2,
                                                   int h, int w) {
  if (blockIdx.z == 8) {
    int bid = blockIdx.y * 2 + blockIdx.x;          // 0..223
    for (int o = bid * 256 + threadIdx.x; o < 147456; o += 224 * 256)
      repack_body(wsrc, wt2, o);
    return;
  }
  const int bi = blockIdx.z;
  const int i = blockIdx.y;
  const int jg = blockIdx.x * 64 + (threadIdx.x & 63);
  const int cg = threadIdx.x >> 6;
  if (jg >= w) return;
  const int H2 = h * 2, W2 = w * 2;
  for (int c = cg; c < 32; c += 4) {
    const float2* p0 = (const float2*)(in + ((size_t)(bi * 32 + c) * H2 + 2 * i) * W2);
    const float2* p1 = (const float2*)(in + ((size_t)(bi * 32 + c) * H2 + 2 * i + 1) * W2);
    float2 r0 = p0[jg];
    float2 r1 = p1[jg];
    llout[((size_t)(bi * 32 + c) * h + i) * w + jg] =
        (r0.x + r0.y + r1.x + r1.y) * 0.5f;
  }
}

// dwt for levels 1/2 (unchanged behavior)
__global__ __launch_bounds__(256) void dwt_kernel(const float* __restrict__ in,
                                                  bf16_t* __restrict__ sub,
                                                  float* __restrict__ llout,
                                                  int h, int w) {
  __shared__ __align__(16) bf16_t lds[64 * 132];
  dwt_body(in, sub, llout, h, w, blockIdx.z, blockIdx.y, blockIdx.x * 64, lds);
}

// ---------------------------------------------------------------------------
// conv12 tile: R12/R14 core VERBATIM (proven replay-stable; used for the
// small levels 1/2). 256 thr, 8x16 px, 64-oc half, acc=32.
// ---------------------------------------------------------------------------
__device__ __forceinline__ void conv_idwt_tile(
    const bf16_t* __restrict__ sub, const bf16_t* __restrict__ wt2,
    const float* __restrict__ nll, const float* __restrict__ nllup,
    const float* __restrict__ bias, float* __restrict__ out,
    int h, int w, int bi, int y0, int x0, int och, uint4* smemV) {
  char* haloS = (char*)smemV;                      // 180 px * 128 B = 23040 B
  char* Bbuf = (char*)smemV + 23040;               // 2 x 8192 B
  float* scr = (float*)((char*)smemV + 23040);     // epilogue alias over Bbuf
  const int tid = threadIdx.x;
  const size_t img_base = (size_t)bi * h * w;

  const int lane = tid & 63;
  const int wv = tid >> 6;                 // wave id (0..3)
  const int m = lane & 31;                 // A-operand m index / D col (oc32)
  const int hw_ = lane >> 5;               // half-wave: k offset hw_*8
  const int il = wv * 2 + (m >> 4);        // local pixel row 0..7
  const int jl = m & 15;
  const int pixA = il * 18 + jl;

  f32x16_t acc[2] = {};

  for (int hk = 0; hk < 2; ++hk) {
    if (hk) __syncthreads();               // pass-0 readers done before overwrite
    for (int it = 0; it < 6; ++it) {
      int flat = it * 256 + tid;           // 1440 slots
      int pix = flat >> 3;
      int ch = flat & 7;
      if (pix < 180) {
        int r = pix / 18;
        int c = pix - r * 18;
        int gy = y0 + r - 1;
        int gx = x0 + c - 1;
        uint4 v = make_uint4(0u, 0u, 0u, 0u);
        if ((unsigned)gy < (unsigned)h && (unsigned)gx < (unsigned)w)
          v = *(const uint4*)(sub + ((img_base + (size_t)gy * w + gx) << 7) +
                              ((hk * 8 + ch) << 3));
        *(uint4*)(haloS + (pix << 7) + ((ch ^ (pix & 7)) << 4)) = v;
      }
    }
    {
      const int th0 = hk;
#pragma unroll
      for (int q = 0; q < 2; ++q) {
        const bf16_t* srcp = wt2 + (((th0 << 4) + (wv << 2) + (q << 1) + och) << 9) + (lane << 3);
        __builtin_amdgcn_global_load_lds(AS_G(srcp),
            AS_L(Bbuf + (((wv << 1) + q) << 10)), 16, 0, 0);
      }
    }
    DRAIN_VM();
    __syncthreads();

    int cur = 0;
    for (int t = 0; t < 9; ++t) {
      if (t < 8) {
        const int thn = ((t + 1) << 1) + hk;
#pragma unroll
        for (int q = 0; q < 2; ++q) {
          const bf16_t* srcp = wt2 + (((thn << 4) + (wv << 2) + (q << 1) + och) << 9) + (lane << 3);
          __builtin_amdgcn_global_load_lds(AS_G(srcp),
              AS_L(Bbuf + ((cur ^ 1) << 13) + (((wv << 1) + q) << 10)), 16, 0, 0);
        }
      }
      const int ky = t / 3;
      const int kx = t - ky * 3;
      const int pix0 = pixA + ky * 18 + kx;
      const int s0 = pix0 & 7;
      const char* hp0 = haloS + (pix0 << 7);
      const char* bp = Bbuf + (cur << 13) + (lane << 4);
#pragma unroll
      for (int kc = 0; kc < 4; ++kc) {
        bf16x8_t b0 = *(const bf16x8_t*)(bp + ((kc << 1) << 10));
        bf16x8_t b1 = *(const bf16x8_t*)(bp + (((kc << 1) + 1) << 10));
        const int cidx = kc * 2 + hw_;
        bf16x8_t a0 = *(const bf16x8_t*)(hp0 + ((cidx ^ s0) << 4));
        acc[0] = __builtin_amdgcn_mfma_f32_32x32x16_bf16(a0, b0, acc[0], 0, 0, 0);
        acc[1] = __builtin_amdgcn_mfma_f32_32x32x16_bf16(a0, b1, acc[1], 0, 0, 0);
      }
      DRAIN_VM();
      __syncthreads();
      cur ^= 1;
    }
  }

  const int W2 = w * 2;
  const int H2 = h * 2;
  const int mh_t = m >> 4;
  const int mm = m & 15;
  const int kw = mm >> 2;
  const int sw = mm & 3;

#pragma unroll
  for (int ph = 0; ph < 4; ++ph) {
    const int nt = ph >> 1;
    const int mh = ph & 1;
    if (ph) __syncthreads();
    if (mh_t == mh) {
#pragma unroll
      for (int reg = 0; reg < 16; ++reg) {
        int row = (reg & 3) + ((reg >> 2) << 3) + (hw_ << 2);
        int px = wv * 32 + row;
        scr[px * 17 + (kw << 2) + sw] = acc[nt][reg];
      }
    }
    __syncthreads();
#pragma unroll
    for (int it = 0; it < 2; ++it) {
      int idx = it * 256 + tid;
      int ox4 = idx & 7;
      int dy = (idx >> 3) & 1;
      int row = (idx >> 4) & 7;
      int k = (idx >> 7) & 3;
      int gy = y0 + row;
      int gx = x0 + ox4 * 2;
      if (gy >= h || gx >= w) continue;
      int p0 = row * 16 + ox4 * 2;
      int p1 = p0 + 1;
      float4 sa = *(const float4*)(&scr[p0 * 17 + (k << 2)]);
      float4 sb = *(const float4*)(&scr[p1 * 17 + (k << 2)]);
      float sg = dy ? -1.f : 1.f;
      float e0 = sa.x + sa.y + sg * (sa.z + sa.w);
      float e1 = sa.x - sa.y + sg * (sa.z - sa.w);
      float e2 = sb.x + sb.y + sg * (sb.z + sb.w);
      float e3 = sb.x - sb.y + sg * (sb.z - sb.w);
      int ch = och * 16 + nt * 8 + mh * 4 + k;
      float* op = out + ((size_t)(bi * 32 + ch) * H2 + 2 * gy + dy) * W2 + 2 * gx;
      float4 o;
      o.x = 0.5f * e0; o.y = 0.5f * e1; o.z = 0.5f * e2; o.w = 0.5f * e3;
      *(float4*)op = o;
    }
  }
}

// ---------------------------------------------------------------------------
// conv12 + sub0 production in ONE dispatch (2368 blocks) -- R14 verbatim.
// ---------------------------------------------------------------------------
__global__ __launch_bounds__(256, 4) void conv12s_kernel(
    const float* __restrict__ x, bf16_t* __restrict__ sub0,
    const bf16_t* __restrict__ sub1, const bf16_t* __restrict__ sub2,
    const bf16_t* __restrict__ wt2, float* __restrict__ nll1raw,
    float* __restrict__ nll2) {
  __shared__ uint4 smemV[2464];            // 39424 B
  const int B = blockIdx.x;
  if (B >= 576) {                          // sub0 production: decode (2,112,8)
    int r = B - 576;
    int bx = r & 1;
    int rr = r >> 1;
    int i = rr % 112;
    int bi = rr / 112;
    dwt_body(x, sub0, nullptr, 112, 112, bi, i, bx * 64, (bf16_t*)smemV);
    return;
  }
  const bf16_t* sub;
  float* outp;
  int hh, bi, by, bx, och;
  if (B < 448) {                           // level 1 (56x56)
    och = B & 1;
    int q = B >> 1;
    bx = q & 3;
    int r = q >> 2;
    by = r % 7;
    bi = r / 7;
    sub = sub1; outp = nll1raw; hh = 56;
  } else {                                 // level 2 (28x28)
    int lb = B - 448;
    och = lb & 1;
    int q = lb >> 1;
    bx = q & 1;
    int r = q >> 1;
    by = r & 3;
    bi = r >> 2;
    sub = sub2; outp = nll2; hh = 28;
  }
  conv_idwt_tile(sub, wt2, nullptr, nullptr, nullptr, outp, hh, hh,
                 bi, by * 8, bx * 16, och, smemV);
}

// ---------------------------------------------------------------------------
// conv0: NEW 512-thr / 16x16-px / 128-oc block with 2x2 wave tiles.
// 8 waves: wm = wv>>1 (rows wm*4..+3), wo = wv&1 (oc half). Wave tile
// M=64 (2 m-tiles) x N=64 (2 n-frags): acc[2][2] = 64 regs; per kc reads
// a0,a1,b0,b1 (4KB) -> 4 MFMAs = 1KB/MFMA operand traffic (R14: 1.5KB) --
// conv0 is LDS-BW-bound, so operand reuse is the lever. Halo staged once
// per hk for the whole 128 oc (R14 duplicated it per och-half) -> FETCH -35%.
// 16 MFMAs per vmcnt-drain (2x R14 density). No upfront B blobs -> live set
// ~105 regs under the (512,4) 128 cap, no spill (R5/R10 lesson).
// LDS = halo 324px*128B (41472) + Bdbuf 2x16KB (32768) = 74240 B -> 2 blk/CU
// (16 waves/CU, same as R14). Epilogue scr[256][17] (17408 B) aliases dead
// Bbuf after the final drained barrier. Grid (7,7,8) = 392 blocks, all
// resident in one round.
// ---------------------------------------------------------------------------
__global__ __launch_bounds__(512, 4) void conv0_kernel(
    const bf16_t* __restrict__ sub, const bf16_t* __restrict__ wt2,
    const float* __restrict__ nll, const float* __restrict__ nllup,
    const float* __restrict__ bias, float* __restrict__ out, int h, int w) {
  __shared__ uint4 smemV[4640];            // 74240 B
  char* haloS = (char*)smemV;              // 324 px * 128 B = 41472 B
  char* Bbuf = (char*)smemV + 41472;       // 2 x 16384 B
  float* scr = (float*)((char*)smemV + 41472);   // [256][17] fp32, alias

  const int tid = threadIdx.x;
  const int bi = blockIdx.z;
  const int y0 = blockIdx.y * 16;
  const int x0 = blockIdx.x * 16;
  const size_t img_base = (size_t)bi * h * w;

  const int lane = tid & 63;
  const int wv = tid >> 6;                 // 0..7
  const int wm = wv >> 1;                  // row group 0..3
  const int wo = wv & 1;                   // oc half
  const int m = lane & 31;
  const int hw_ = lane >> 5;
  const int pixA = (wm * 4 + (m >> 4)) * 18 + (m & 15);

  f32x16_t acc[2][2] = {};                 // [mt][nt]

  for (int hk = 0; hk < 2; ++hk) {
    if (hk) __syncthreads();               // pass-0 readers done before overwrite
    // ---- stage halo half: 324 px x 8 chunks of 16B, zero-filled borders ----
    for (int it = 0; it < 6; ++it) {
      int flat = it * 512 + tid;           // 2592 slots
      int pix = flat >> 3;
      int ch = flat & 7;
      if (pix < 324) {
        int r = pix / 18;
        int c = pix - r * 18;
        int gy = y0 + r - 1;
        int gx = x0 + c - 1;
        uint4 v = make_uint4(0u, 0u, 0u, 0u);
        if ((unsigned)gy < (unsigned)h && (unsigned)gx < (unsigned)w)
          v = *(const uint4*)(sub + ((img_base + (size_t)gy * w + gx) << 7) +
                              ((hk * 8 + ch) << 3));
        *(uint4*)(haloS + (pix << 7) + ((ch ^ (pix & 7)) << 4)) = v;
      }
    }
    // ---- stage B(0): 16 frags, 2 per wave; fi = kc*4 + nt*2 + wc ----
    {
      const int th0 = hk;
#pragma unroll
      for (int q = 0; q < 2; ++q) {
        const int fi = wv * 2 + q;
        const bf16_t* srcp = wt2 + (((th0 << 4) + fi) << 9) + (lane << 3);
        __builtin_amdgcn_global_load_lds(AS_G(srcp),
            AS_L(Bbuf + (fi << 10)), 16, 0, 0);
      }
    }
    DRAIN_VM();                            // B(0) landed
    __syncthreads();                       // halo + B(0) published

    int cur = 0;
    for (int t = 0; t < 9; ++t) {
      if (t < 8) {                         // fire-and-forget next tap's B
        const int thn = ((t + 1) << 1) + hk;
#pragma unroll
        for (int q = 0; q < 2; ++q) {
          const int fi = wv * 2 + q;
          const bf16_t* srcp = wt2 + (((thn << 4) + fi) << 9) + (lane << 3);
          __builtin_amdgcn_global_load_lds(AS_G(srcp),
              AS_L(Bbuf + ((cur ^ 1) << 14) + (fi << 10)), 16, 0, 0);
        }
      }
      const int ky = t / 3;
      const int kx = t - ky * 3;
      const int pix0 = pixA + ky * 18 + kx;
      const int pix1 = pix0 + 36;          // mt=1: +2 pixel rows
      const int s0 = pix0 & 7;
      const int s1 = pix1 & 7;
      const char* hp0 = haloS + (pix0 << 7);
      const char* hp1 = haloS + (pix1 << 7);
      const char* bp = Bbuf + (cur << 14) + (lane << 4);
#pragma unroll
      for (int kc = 0; kc < 4; ++kc) {
        bf16x8_t b0 = *(const bf16x8_t*)(bp + (((kc << 2) + wo) << 10));
        bf16x8_t b1 = *(const bf16x8_t*)(bp + (((kc << 2) + 2 + wo) << 10));
        const int cidx = kc * 2 + hw_;
        bf16x8_t a0 = *(const bf16x8_t*)(hp0 + ((cidx ^ s0) << 4));
        bf16x8_t a1 = *(const bf16x8_t*)(hp1 + ((cidx ^ s1) << 4));
        acc[0][0] = __builtin_amdgcn_mfma_f32_32x32x16_bf16(a0, b0, acc[0][0], 0, 0, 0);
        acc[0][1] = __builtin_amdgcn_mfma_f32_32x32x16_bf16(a0, b1, acc[0][1], 0, 0, 0);
        acc[1][0] = __builtin_amdgcn_mfma_f32_32x32x16_bf16(a1, b0, acc[1][0], 0, 0, 0);
        acc[1][1] = __builtin_amdgcn_mfma_f32_32x32x16_bf16(a1, b1, acc[1][1], 0, 0, 0);
      }
      DRAIN_VM();                          // B(t+1) landed
      __syncthreads();                     // my B(t)/halo reads done
      cur ^= 1;
    }
  }

  // ---- IDWT epilogue: 8 phases (wo_p, nt_p, mh_p) of 16 oc over scr[256][17]
  // D layout (m74/m101): rowi = (reg&3)+8*(reg>>2)+4*hw_ (0..31), col(oc32)=m;
  // px = (wm*4 + mt*2 + (rowi>>4))*16 + (rowi&15).
  const int W2 = w * 2;
  const int H2 = h * 2;
  const int hu = h >> 1, wu = w >> 1;
  const int mh_t = m >> 4;
  const int mm = m & 15;
  const int kw = mm >> 2;
  const int sw = mm & 3;

#pragma unroll
  for (int ph = 0; ph < 8; ++ph) {
    const int wo_p = ph >> 2;
    const int nt_p = (ph >> 1) & 1;
    const int mh_p = ph & 1;
    if (ph) __syncthreads();               // prior read phase done
    if (wo == wo_p && mh_t == mh_p) {
#pragma unroll
      for (int mt = 0; mt < 2; ++mt) {
#pragma unroll
        for (int reg = 0; reg < 16; ++reg) {
          int rowi = (reg & 3) + ((reg >> 2) << 3) + (hw_ << 2);
          int px = (wm * 4 + mt * 2 + (rowi >> 4)) * 16 + (rowi & 15);
          scr[px * 17 + (kw << 2) + sw] = acc[mt][nt_p][reg];
        }
      }
    }
    __syncthreads();
    // read: 4 ch x 16 rows x 8 col-pairs x 2 dy = 1024 tasks -> 2 iters
#pragma unroll
    for (int it = 0; it < 2; ++it) {
      int idx = it * 512 + tid;
      int ox4 = idx & 7;
      int dy = (idx >> 3) & 1;
      int row = (idx >> 4) & 15;
      int k = (idx >> 8) & 3;
      int gy = y0 + row;
      int gx = x0 + ox4 * 2;
      if (gy >= h || gx >= w) continue;
      int p0 = row * 16 + ox4 * 2;
      int p1 = p0 + 1;
      float4 sa = *(const float4*)(&scr[p0 * 17 + (k << 2)]);
      float4 sb = *(const float4*)(&scr[p1 * 17 + (k << 2)]);
      float sg = dy ? -1.f : 1.f;
      float e0 = sa.x + sa.y + sg * (sa.z + sa.w);
      float e1 = sa.x - sa.y + sg * (sa.z - sa.w);
      float e2 = sb.x + sb.y + sg * (sb.z + sb.w);
      float e3 = sb.x - sb.y + sg * (sb.z - sb.w);
      int ch = wo_p * 16 + nt_p * 8 + mh_p * 4 + k;   // output channel 0..31
      float n0 = 0.f, n1 = 0.f;
      if (nll != nullptr) {
        const float* np = nll + ((size_t)(bi * 32 + ch) * h + gy) * w + gx;
        float2 nv = *(const float2*)np;
        n0 = nv.x; n1 = nv.y;
      }
      if (nllup != nullptr) {              // deeper level, half res, IDWT-linear fold
        float u = nllup[((size_t)(bi * 32 + ch) * hu + (gy >> 1)) * wu + (gx >> 1)];
        n0 += 0.5f * u;
        n1 += 0.5f * u;
      }
      float bv = (bias != nullptr) ? bias[ch] : 0.f;
      float4 o;
      o.x = 0.5f * e0 + 0.5f * n0 + bv;
      o.y = 0.5f * e1 + 0.5f * n0 + bv;
      o.z = 0.5f * e2 + 0.5f * n1 + bv;
      o.w = 0.5f * e3 + 0.5f * n1 + bv;
      float* op = out + ((size_t)(bi * 32 + ch) * H2 + 2 * gy + dy) * W2 + 2 * gx;
      *(float4*)op = o;
    }
  }
}

// ---------------------------------------------------------------------------
// Workspace layout (bytes, peak 66,125,824):
//   wt2  @ 0           (294,912)
//   sub0 @ 294,912     (25,690,112)
//   sub1 @ 25,985,024  (6,422,528)
//   sub2 @ 32,407,552  (1,605,632)
//   ll0  @ 34,013,184  (12,845,056)
//   ll1  @ 46,858,240  (3,211,264)
//   nll2 @ 50,069,504  (3,211,264)
//   nll1 @ 53,280,768  (12,845,056)  -> end 66,125,824
// ---------------------------------------------------------------------------
extern "C" void kernel_launch(void* const* d_in, const int* in_sizes, int n_in,
                              void* d_out, int out_size, void* d_ws, size_t ws_size,
                              hipStream_t stream) {
  if (ws_size < 66125824u) return;

  const float* x = (const float*)d_in[0];
  const float* weight = (const float*)d_in[1];
  const float* bias = (const float*)d_in[2];
  float* out = (float*)d_out;
  char* ws = (char*)d_ws;

  bf16_t* wt2 = (bf16_t*)(ws);
  bf16_t* sub0 = (bf16_t*)(ws + 294912);
  bf16_t* sub1 = (bf16_t*)(ws + 25985024);
  bf16_t* sub2 = (bf16_t*)(ws + 32407552);
  float* ll0 = (float*)(ws + 34013184);
  float* ll1 = (float*)(ws + 46858240);
  float* nll2 = (float*)(ws + 50069504);
  float* nll1 = (float*)(ws + 53280768);

  // ll0 (x -> ll0) + weight repack; sub0 production lives in conv12s
  ll0r_kernel<<<dim3(2, 112, 9), 256, 0, stream>>>(x, ll0, weight, wt2, 112, 112);
  dwt_kernel<<<dim3(1, 56, 8), 256, 0, stream>>>(ll0, sub1, ll1, 56, 56);
  dwt_kernel<<<dim3(1, 28, 8), 256, 0, stream>>>(ll1, sub2, nullptr, 28, 28);
  // levels 1+2 conv+idwt AND sub0 production in one 2368-block dispatch
  conv12s_kernel<<<2368, 256, 0, stream>>>(x, sub0, sub1, sub2, wt2, nll1, nll2);
  // level 0: 512-thr 2x2-wave-tile conv+idwt (sub0 + nll1 + 0.5*up(nll2) + bias)
  conv0_kernel<<<dim3(7, 7, 8), 512, 0, stream>>>(sub0, wt2, nll1, nll2, bias, out, 112, 112);
}

// Round 16
// 177.897 us; speedup vs baseline: 1.1490x; 1.1490x over previous
//
#include <hip/hip_runtime.h>

typedef __bf16 bf16_t;
typedef __bf16 bf16x4_t __attribute__((ext_vector_type(4)));
typedef __bf16 bf16x8_t __attribute__((ext_vector_type(8)));
typedef float f32x16_t __attribute__((ext_vector_type(16)));

#define AS_G(p) ((const __attribute__((address_space(1))) void*)(p))
#define AS_L(p) ((__attribute__((address_space(3))) void*)(p))
// R11 post-mortem: vmcnt drain before a barrier publishing global_load_lds
// data must be EXPLICIT (__syncthreads alone was replay-flaky).
#define DRAIN_VM() asm volatile("s_waitcnt vmcnt(0)" ::: "memory")

// ---------------------------------------------------------------------------
// Weight repack (oc, ic, ky, kx) fp32 -> bf16 in MFMA B-fragment order:
//   frag f = th*16 + kc*4 + nt*2 + wc,  th = t*2+hk  (frag = 1024 B, lane*16B)
//   lane -> oc = wc*64 + nt*32 + (lane&31); ic = (hk*8 + kc*2 + (lane>>5))*8 + e
// ---------------------------------------------------------------------------
__device__ __forceinline__ void repack_body(const float* __restrict__ w,
                                            bf16_t* __restrict__ wt2,
                                            int o) {
  int e = o & 7;
  int lane = (o >> 3) & 63;
  int f = o >> 9;
  int wc = f & 1;
  int nt = (f >> 1) & 1;
  int kc = (f >> 2) & 3;
  int hk = (f >> 4) & 1;
  int t = f >> 5;
  int oc = wc * 64 + nt * 32 + (lane & 31);
  int ic = (hk * 8 + kc * 2 + (lane >> 5)) * 8 + e;
  wt2[o] = (bf16_t)w[((size_t)oc * 128 + ic) * 9 + t];
}

// ---------------------------------------------------------------------------
// DWT body (explicit block coords): in fp32 (B,32,2h,2w) ->
//   sub bf16 NHWC (B,h,w,128) ci=4c+q  [+ ll fp32 (B,32,h,w)]
// ---------------------------------------------------------------------------
__device__ __forceinline__ void dwt_body(const float* __restrict__ in,
                                         bf16_t* __restrict__ sub,
                                         float* __restrict__ llout,
                                         int h, int w, int bi, int i, int j0,
                                         bf16_t* lds) {
  const int tid = threadIdx.x;
  const int j = tid & 63;
  const int cg = tid >> 6;
  const int jg = j0 + j;
  const bool jok = jg < w;
  const int H2 = h * 2, W2 = w * 2;
  for (int c = cg; c < 32; c += 4) {
    float va = 0.f, vb = 0.f, vc = 0.f, vd = 0.f;
    if (jok) {
      const float2* p0 = (const float2*)(in + ((size_t)(bi * 32 + c) * H2 + 2 * i) * W2);
      const float2* p1 = (const float2*)(in + ((size_t)(bi * 32 + c) * H2 + 2 * i + 1) * W2);
      float2 r0 = p0[jg];
      float2 r1 = p1[jg];
      va = r0.x; vb = r0.y; vc = r1.x; vd = r1.y;
    }
    float ll = (va + vb + vc + vd) * 0.5f;
    float lh = (va - vb + vc - vd) * 0.5f;
    float hl = (va + vb - vc - vd) * 0.5f;
    float hh = (va - vb - vc + vd) * 0.5f;
    bf16x4_t q;
    q.x = (bf16_t)ll; q.y = (bf16_t)lh; q.z = (bf16_t)hl; q.w = (bf16_t)hh;
    *(bf16x4_t*)(&lds[j * 132 + c * 4]) = q;
    if (llout != nullptr && jok)
      llout[((size_t)(bi * 32 + c) * h + i) * w + jg] = ll;
  }
  __syncthreads();
  const size_t obase = ((size_t)bi * h + i) * w;
  for (int it = 0; it < 8; ++it) {
    int flat = it * 256 + tid;
    int jj = flat >> 5;
    int c4 = flat & 31;
    if (j0 + jj < w) {
      bf16x4_t q = *(const bf16x4_t*)(&lds[jj * 132 + c4 * 4]);
      *(bf16x4_t*)(sub + ((obase + j0 + jj) << 7) + c4 * 4) = q;
    }
  }
}

// ---------------------------------------------------------------------------
// dwt1 DIRECT FROM x (ll0 eliminated): dwt1's inputs are exact 4x4 Haar
// averages of x, so a,b,c,d = 0.5*(2x2 sums of x) -- bit-identical fp32
// arithmetic to the old ll0r+dwt1 chain, one dispatch instead of two, and
// each x pixel is read exactly once (coalesced float4 per lane).
// Grid (1,56,9): z<8 -> dwt1 row (bi=z, i=y); z==8 slab -> weight repack.
// Outputs: sub1 bf16 NHWC (B,56,56,128) + ll1 fp32 (B,32,56,56).
// ---------------------------------------------------------------------------
__global__ __launch_bounds__(256) void dwt1x_kernel(const float* __restrict__ x,
                                                    bf16_t* __restrict__ sub1,
                                                    float* __restrict__ ll1,
                                                    const float* __restrict__ wsrc,
                                                    bf16_t* __restrict__ wt2) {
  __shared__ __align__(16) bf16_t lds[64 * 132];
  if (blockIdx.z == 8) {
    int bid = blockIdx.y;                  // 0..55
    for (int o = bid * 256 + threadIdx.x; o < 147456; o += 56 * 256)
      repack_body(wsrc, wt2, o);
    return;
  }
  const int bi = blockIdx.z;
  const int i = blockIdx.y;                // 0..55
  const int tid = threadIdx.x;
  const int j = tid & 63;
  const int cg = tid >> 6;
  const int h = 56, w = 56;
  const bool jok = j < w;
  for (int c = cg; c < 32; c += 4) {
    float va = 0.f, vb = 0.f, vc = 0.f, vd = 0.f;
    if (jok) {
      const float* base = x + ((size_t)(bi * 32 + c) * 224 + 4 * i) * 224;
      float4 p0 = ((const float4*)(base))[j];
      float4 p1 = ((const float4*)(base + 224))[j];
      float4 p2 = ((const float4*)(base + 448))[j];
      float4 p3 = ((const float4*)(base + 672))[j];
      va = (p0.x + p0.y + p1.x + p1.y) * 0.5f;   // ll0[2i][2j]
      vb = (p0.z + p0.w + p1.z + p1.w) * 0.5f;   // ll0[2i][2j+1]
      vc = (p2.x + p2.y + p3.x + p3.y) * 0.5f;   // ll0[2i+1][2j]
      vd = (p2.z + p2.w + p3.z + p3.w) * 0.5f;   // ll0[2i+1][2j+1]
    }
    float ll = (va + vb + vc + vd) * 0.5f;
    float lh = (va - vb + vc - vd) * 0.5f;
    float hl = (va + vb - vc - vd) * 0.5f;
    float hh = (va - vb - vc + vd) * 0.5f;
    bf16x4_t q;
    q.x = (bf16_t)ll; q.y = (bf16_t)lh; q.z = (bf16_t)hl; q.w = (bf16_t)hh;
    *(bf16x4_t*)(&lds[j * 132 + c * 4]) = q;
    if (jok)
      ll1[((size_t)(bi * 32 + c) * h + i) * w + j] = ll;
  }
  __syncthreads();
  const size_t obase = ((size_t)bi * h + i) * w;
  for (int it = 0; it < 8; ++it) {
    int flat = it * 256 + tid;
    int jj = flat >> 5;
    int c4 = flat & 31;
    if (jj < w) {
      bf16x4_t q = *(const bf16x4_t*)(&lds[jj * 132 + c4 * 4]);
      *(bf16x4_t*)(sub1 + ((obase + jj) << 7) + c4 * 4) = q;
    }
  }
}

// dwt for level 2 (ll1 -> sub2)
__global__ __launch_bounds__(256) void dwt_kernel(const float* __restrict__ in,
                                                  bf16_t* __restrict__ sub,
                                                  float* __restrict__ llout,
                                                  int h, int w) {
  __shared__ __align__(16) bf16_t lds[64 * 132];
  dwt_body(in, sub, llout, h, w, blockIdx.z, blockIdx.y, blockIdx.x * 64, lds);
}

// ---------------------------------------------------------------------------
// Fused conv 3x3 (pad1, 128ic -> 64oc-HALF, MFMA 32x32x16 bf16) + IDWT epi.
// R12/R14 core VERBATIM (best passing: ~58us conv0, replay-stable). B
// tap-tile (8 frags x 1KB) double-buffered, filled by global_load_lds; per
// tap-phase: issue next tap's 8 DMAs (2/wave) -> ds_read B + A -> 8 MFMA ->
// DRAIN_VM + barrier. Epilogue: scr[128][17] fp32 aliases the dead B dbuf.
// LDS = 23040 halo + 16384 Bdbuf = 39424 B -> 4 blocks/CU.
// (R15 lesson #3: acc=64 variants spill at every useful occupancy point --
// acc=32 + 4 blk/CU is this conv's stable optimum.)
// ---------------------------------------------------------------------------
__device__ __forceinline__ void conv_idwt_tile(
    const bf16_t* __restrict__ sub, const bf16_t* __restrict__ wt2,
    const float* __restrict__ nll, const float* __restrict__ nllup,
    const float* __restrict__ bias, float* __restrict__ out,
    int h, int w, int bi, int y0, int x0, int och, uint4* smemV) {
  char* haloS = (char*)smemV;                      // 180 px * 128 B = 23040 B
  char* Bbuf = (char*)smemV + 23040;               // 2 x 8192 B
  float* scr = (float*)((char*)smemV + 23040);     // epilogue alias over Bbuf
  const int tid = threadIdx.x;
  const size_t img_base = (size_t)bi * h * w;

  const int lane = tid & 63;
  const int wv = tid >> 6;                 // wave id (0..3)
  const int m = lane & 31;                 // A-operand m index / D col (oc32)
  const int hw_ = lane >> 5;               // half-wave: k offset hw_*8
  const int il = wv * 2 + (m >> 4);        // local pixel row 0..7
  const int jl = m & 15;
  const int pixA = il * 18 + jl;

  f32x16_t acc[2] = {};

  for (int hk = 0; hk < 2; ++hk) {
    if (hk) __syncthreads();               // pass-0 readers done before overwrite
    // ---- stage halo half: 180 px x 8 chunks of 16B, zero-filled borders ----
    for (int it = 0; it < 6; ++it) {
      int flat = it * 256 + tid;           // 1440 slots
      int pix = flat >> 3;
      int ch = flat & 7;
      if (pix < 180) {
        int r = pix / 18;
        int c = pix - r * 18;
        int gy = y0 + r - 1;
        int gx = x0 + c - 1;
        uint4 v = make_uint4(0u, 0u, 0u, 0u);
        if ((unsigned)gy < (unsigned)h && (unsigned)gx < (unsigned)w)
          v = *(const uint4*)(sub + ((img_base + (size_t)gy * w + gx) << 7) +
                              ((hk * 8 + ch) << 3));
        *(uint4*)(haloS + (pix << 7) + ((ch ^ (pix & 7)) << 4)) = v;
      }
    }
    // ---- stage B for t=0 of this hk into buf 0 (2 frag-DMAs per wave) ----
    {
      const int th0 = hk;                  // th = 0*2 + hk
#pragma unroll
      for (int q = 0; q < 2; ++q) {
        const bf16_t* srcp = wt2 + (((th0 << 4) + (wv << 2) + (q << 1) + och) << 9) + (lane << 3);
        __builtin_amdgcn_global_load_lds(AS_G(srcp),
            AS_L(Bbuf + (((wv << 1) + q) << 10)), 16, 0, 0);
      }
    }
    DRAIN_VM();                            // B(0) DMA landed in LDS
    __syncthreads();                       // halo + B(0) published

    int cur = 0;
    for (int t = 0; t < 9; ++t) {
      if (t < 8) {                         // fire-and-forget next tap's B
        const int thn = ((t + 1) << 1) + hk;
#pragma unroll
        for (int q = 0; q < 2; ++q) {
          const bf16_t* srcp = wt2 + (((thn << 4) + (wv << 2) + (q << 1) + och) << 9) + (lane << 3);
          __builtin_amdgcn_global_load_lds(AS_G(srcp),
              AS_L(Bbuf + ((cur ^ 1) << 13) + (((wv << 1) + q) << 10)), 16, 0, 0);
        }
      }
      const int ky = t / 3;
      const int kx = t - ky * 3;
      const int pix0 = pixA + ky * 18 + kx;
      const int s0 = pix0 & 7;
      const char* hp0 = haloS + (pix0 << 7);
      const char* bp = Bbuf + (cur << 13) + (lane << 4);
#pragma unroll
      for (int kc = 0; kc < 4; ++kc) {
        bf16x8_t b0 = *(const bf16x8_t*)(bp + ((kc << 1) << 10));
        bf16x8_t b1 = *(const bf16x8_t*)(bp + (((kc << 1) + 1) << 10));
        const int cidx = kc * 2 + hw_;     // 16B chunk within the 64-ic half
        bf16x8_t a0 = *(const bf16x8_t*)(hp0 + ((cidx ^ s0) << 4));
        acc[0] = __builtin_amdgcn_mfma_f32_32x32x16_bf16(a0, b0, acc[0], 0, 0, 0);
        acc[1] = __builtin_amdgcn_mfma_f32_32x32x16_bf16(a0, b1, acc[1], 0, 0, 0);
      }
      DRAIN_VM();                          // B(t+1) DMA landed in LDS
      __syncthreads();                     // my B(t)/halo reads done; publish B(t+1)
      cur ^= 1;
    }
  }

  // ---- IDWT epilogue: 4 phases of 16 oc over scr[128][17] (aliases dead
  // Bbuf; final tap barrier+drain guarantees nothing lands late). ----
  // D layout (m74/m101): row = (reg&3)+8*(reg>>2)+4*hw_ (0..31), col(oc32)=m;
  // pixel px = wv*32 + row (row-major 8x16 tile).
  const int W2 = w * 2;
  const int H2 = h * 2;
  const int hu = h >> 1, wu = w >> 1;
  const int mh_t = m >> 4;                 // which 16-oc half this lane holds
  const int mm = m & 15;
  const int kw = mm >> 2;                  // channel-within-16 (write side)
  const int sw = mm & 3;                   // subband q

#pragma unroll
  for (int ph = 0; ph < 4; ++ph) {
    const int nt = ph >> 1;
    const int mh = ph & 1;
    if (ph) __syncthreads();               // prior read phase done
    if (mh_t == mh) {
#pragma unroll
      for (int reg = 0; reg < 16; ++reg) {
        int row = (reg & 3) + ((reg >> 2) << 3) + (hw_ << 2);
        int px = wv * 32 + row;            // 0..127
        scr[px * 17 + (kw << 2) + sw] = acc[nt][reg];
      }
    }
    __syncthreads();
    // read phase: 4 ch x 8 rows x 8 col-pairs x 2 dy = 512 tasks -> 2 iters
#pragma unroll
    for (int it = 0; it < 2; ++it) {
      int idx = it * 256 + tid;
      int ox4 = idx & 7;
      int dy = (idx >> 3) & 1;
      int row = (idx >> 4) & 7;
      int k = (idx >> 7) & 3;
      int gy = y0 + row;
      int gx = x0 + ox4 * 2;
      if (gy >= h || gx >= w) continue;
      int p0 = row * 16 + ox4 * 2;
      int p1 = p0 + 1;
      float4 sa = *(const float4*)(&scr[p0 * 17 + (k << 2)]);
      float4 sb = *(const float4*)(&scr[p1 * 17 + (k << 2)]);
      float sg = dy ? -1.f : 1.f;
      float e0 = sa.x + sa.y + sg * (sa.z + sa.w);
      float e1 = sa.x - sa.y + sg * (sa.z - sa.w);
      float e2 = sb.x + sb.y + sg * (sb.z + sb.w);
      float e3 = sb.x - sb.y + sg * (sb.z - sb.w);
      int ch = och * 16 + nt * 8 + mh * 4 + k;   // output channel 0..31
      float n0 = 0.f, n1 = 0.f;
      if (nll != nullptr) {
        const float* np = nll + ((size_t)(bi * 32 + ch) * h + gy) * w + gx;
        float2 nv = *(const float2*)np;
        n0 = nv.x; n1 = nv.y;
      }
      if (nllup != nullptr) {              // deeper level, half res, IDWT-linear fold
        float u = nllup[((size_t)(bi * 32 + ch) * hu + (gy >> 1)) * wu + (gx >> 1)];
        n0 += 0.5f * u;
        n1 += 0.5f * u;
      }
      float bv = (bias != nullptr) ? bias[ch] : 0.f;
      float4 o;
      o.x = 0.5f * e0 + 0.5f * n0 + bv;
      o.y = 0.5f * e1 + 0.5f * n0 + bv;
      o.z = 0.5f * e2 + 0.5f * n1 + bv;
      o.w = 0.5f * e3 + 0.5f * n1 + bv;
      float* op = out + ((size_t)(bi * 32 + ch) * H2 + 2 * gy + dy) * W2 + 2 * gx;
      *(float4*)op = o;
    }
  }
}

// conv0: grid (14,14,8): x = bx*2 + och; has nll + nllup + bias
__global__ __launch_bounds__(256, 4) void conv_idwt_kernel(
    const bf16_t* __restrict__ sub, const bf16_t* __restrict__ wt2,
    const float* __restrict__ nll, const float* __restrict__ nllup,
    const float* __restrict__ bias, float* __restrict__ out, int h, int w) {
  __shared__ uint4 smemV[2464];            // 39424 B (halo 23040 + Bdbuf 16384)
  conv_idwt_tile(sub, wt2, nll, nllup, bias, out, h, w,
                 blockIdx.z, blockIdx.y * 8, (blockIdx.x >> 1) * 16,
                 blockIdx.x & 1, smemV);
}

// ---------------------------------------------------------------------------
// conv12 + sub0 production in ONE dispatch (2368 blocks) -- R14 verbatim:
//   [0,448)    level-1 conv+idwt  (compute-bound)
//   [448,576)  level-2 conv+idwt  (compute-bound)
//   [576,2368) dwt0 sub0 blocks   (memory-bound; x -> sub0 bf16 NHWC)
// ---------------------------------------------------------------------------
__global__ __launch_bounds__(256, 4) void conv12s_kernel(
    const float* __restrict__ x, bf16_t* __restrict__ sub0,
    const bf16_t* __restrict__ sub1, const bf16_t* __restrict__ sub2,
    const bf16_t* __restrict__ wt2, float* __restrict__ nll1raw,
    float* __restrict__ nll2) {
  __shared__ uint4 smemV[2464];            // 39424 B (dwt path uses 16896 B)
  const int B = blockIdx.x;
  if (B >= 576) {                          // sub0 production: decode (2,112,8)
    int r = B - 576;                       // 0..1791
    int bx = r & 1;
    int rr = r >> 1;
    int i = rr % 112;
    int bi = rr / 112;
    dwt_body(x, sub0, nullptr, 112, 112, bi, i, bx * 64, (bf16_t*)smemV);
    return;
  }
  const bf16_t* sub;
  float* outp;
  int hh, bi, by, bx, och;
  if (B < 448) {                           // level 1 (56x56): 2 och x 4 bx x 7 by x 8 bi
    och = B & 1;
    int q = B >> 1;
    bx = q & 3;
    int r = q >> 2;
    by = r % 7;
    bi = r / 7;
    sub = sub1; outp = nll1raw; hh = 56;
  } else {                                 // level 2 (28x28): 2 och x 2 bx x 4 by x 8 bi
    int lb = B - 448;
    och = lb & 1;
    int q = lb >> 1;
    bx = q & 1;
    int r = q >> 1;
    by = r & 3;
    bi = r >> 2;
    sub = sub2; outp = nll2; hh = 28;
  }
  conv_idwt_tile(sub, wt2, nullptr, nullptr, nullptr, outp, hh, hh,
                 bi, by * 8, bx * 16, och, smemV);
}

// ---------------------------------------------------------------------------
// Workspace layout (bytes, peak 66,125,824; ll0 slot now unused):
//   wt2  @ 0           (294,912)
//   sub0 @ 294,912     (25,690,112)
//   sub1 @ 25,985,024  (6,422,528)
//   sub2 @ 32,407,552  (1,605,632)
//   ll1  @ 46,858,240  (3,211,264)
//   nll2 @ 50,069,504  (3,211,264)
//   nll1 @ 53,280,768  (12,845,056)  -> end 66,125,824
// ---------------------------------------------------------------------------
extern "C" void kernel_launch(void* const* d_in, const int* in_sizes, int n_in,
                              void* d_out, int out_size, void* d_ws, size_t ws_size,
                              hipStream_t stream) {
  if (ws_size < 66125824u) return;

  const float* x = (const float*)d_in[0];
  const float* weight = (const float*)d_in[1];
  const float* bias = (const float*)d_in[2];
  float* out = (float*)d_out;
  char* ws = (char*)d_ws;

  bf16_t* wt2 = (bf16_t*)(ws);
  bf16_t* sub0 = (bf16_t*)(ws + 294912);
  bf16_t* sub1 = (bf16_t*)(ws + 25985024);
  bf16_t* sub2 = (bf16_t*)(ws + 32407552);
  float* ll1 = (float*)(ws + 46858240);
  float* nll2 = (float*)(ws + 50069504);
  float* nll1 = (float*)(ws + 53280768);

  // dwt1 straight from x (ll0 eliminated) + weight repack slab
  dwt1x_kernel<<<dim3(1, 56, 9), 256, 0, stream>>>(x, sub1, ll1, weight, wt2);
  // dwt2: ll1 -> sub2
  dwt_kernel<<<dim3(1, 28, 8), 256, 0, stream>>>(ll1, sub2, nullptr, 28, 28);
  // levels 1+2 conv+idwt AND sub0 production in one 2368-block dispatch
  conv12s_kernel<<<2368, 256, 0, stream>>>(x, sub0, sub1, sub2, wt2, nll1, nll2);
  // level 0 conv+idwt consumes sub0 + nll1raw + 0.5*up(nll2), adds bias
  conv_idwt_kernel<<<dim3(14, 14, 8), 256, 0, stream>>>(sub0, wt2, nll1, nll2, bias, out, 112, 112);
}